// Round 4
// baseline (309.099 us; speedup 1.0000x reference)
//
#include <hip/hip_runtime.h>
#include <math.h>

#define HIDDEN 1024
#define SEQ 2048
#define NF 94
#define PI 256
#define NUM_TOKEN 5

typedef float vfloat4 __attribute__((ext_vector_type(4)));

__device__ __forceinline__ float gelu_exact(float a) {
    return 0.5f * a * (1.0f + erff(a * 0.70710678118654752f));
}

// ---------------------------------------------------------------------------
// Kernel A: streaming path for ALL tokens, assuming num_emb == 0.
// Wave-per-token, no LDS, no barriers, minimal registers -> max occupancy to
// hide the random W_word row-gather latency. Active tokens get overwritten by
// kernel B afterwards.
// ---------------------------------------------------------------------------
__global__ __launch_bounds__(256)
void text_ln_kernel(const int* __restrict__ ids,
                    const float* __restrict__ Ww,
                    const float* __restrict__ Wp,
                    const float* __restrict__ Wt,
                    const float* __restrict__ lng,
                    const float* __restrict__ lnb,
                    float* __restrict__ out,
                    int tokens)
{
    const int lane  = threadIdx.x & 63;
    const int wv    = threadIdx.x >> 6;
    const int token = blockIdx.x * 4 + wv;
    if (token >= tokens) return;
    const int s    = token & (SEQ - 1);
    const int id   = ids[token];
    const int col0 = lane * 4;

    const float* wrow = Ww + (size_t)id * HIDDEN;
    const float* prow = Wp + (size_t)s  * HIDDEN;

    float x[4][4];
    #pragma unroll
    for (int j = 0; j < 4; ++j) {
        const int off = j * 256 + col0;
        const float4 aw = *(const float4*)(wrow + off);
        const float4 ap = *(const float4*)(prow + off);
        const float4 at = *(const float4*)(Wt   + off);
        x[j][0] = aw.x + ap.x + at.x;
        x[j][1] = aw.y + ap.y + at.y;
        x[j][2] = aw.z + ap.z + at.z;
        x[j][3] = aw.w + ap.w + at.w;
    }

    float sm = 0.0f, sq = 0.0f;
    #pragma unroll
    for (int j = 0; j < 4; ++j)
        #pragma unroll
        for (int c = 0; c < 4; ++c) { sm += x[j][c]; sq += x[j][c] * x[j][c]; }
    #pragma unroll
    for (int off = 32; off > 0; off >>= 1) {
        sm += __shfl_xor(sm, off, 64);
        sq += __shfl_xor(sq, off, 64);
    }
    const float mu   = sm * (1.0f / HIDDEN);
    const float var  = sq * (1.0f / HIDDEN) - mu * mu;
    const float rstd = rsqrtf(var + 1e-12f);

    float* orow = out + (size_t)token * HIDDEN;
    #pragma unroll
    for (int j = 0; j < 4; ++j) {
        const int off = j * 256 + col0;
        const float4 g4 = *(const float4*)(lng + off);
        const float4 b4 = *(const float4*)(lnb + off);
        vfloat4 o;
        o.x = (x[j][0] - mu) * rstd * g4.x + b4.x;
        o.y = (x[j][1] - mu) * rstd * g4.y + b4.y;
        o.z = (x[j][2] - mu) * rstd * g4.z + b4.z;
        o.w = (x[j][3] - mu) * rstd * g4.w + b4.w;
        __builtin_nontemporal_store(o, (vfloat4*)(orow + off));
    }
}

// ---------------------------------------------------------------------------
// Kernel B: fixup for active numeric tokens (~0-2 expected in 16384).
// Each wave ballots 64 tokens; zero mask -> immediate exit. For each active
// token the whole wave recomputes text + numeric MLP + both LayerNorms and
// overwrites the output row. Heavy registers here don't affect kernel A.
// ---------------------------------------------------------------------------
__global__ __launch_bounds__(256)
void numeric_fix_kernel(const int* __restrict__ ids,
                        const float* __restrict__ vals,
                        const int* __restrict__ fmts,
                        const float* __restrict__ Ww,
                        const float* __restrict__ Wp,
                        const float* __restrict__ Wt,
                        const float* __restrict__ lng,
                        const float* __restrict__ lnb,
                        const float* __restrict__ w1,
                        const float* __restrict__ b1,
                        const float* __restrict__ w2,
                        const float* __restrict__ b2,
                        const float* __restrict__ plng,
                        const float* __restrict__ plnb,
                        float* __restrict__ out,
                        int tokens)
{
    const int lane = threadIdx.x & 63;
    const int wv   = threadIdx.x >> 6;
    const int base = (blockIdx.x * 4 + wv) * 64;
    if (base >= tokens) return;

    const int   myid  = ids[base + lane];
    const float myval = vals[base + lane];
    unsigned long long mask = __ballot((myid == NUM_TOKEN) && !isnan(myval));

    const int col0 = lane * 4;

    while (mask) {
        const int t = __ffsll((unsigned long long)mask) - 1;
        mask &= mask - 1;
        const int token = base + t;
        const int s     = token & (SEQ - 1);

        const float vraw = __shfl(myval, t, 64);
        const int   fmt  = fmts[token];

        const double    v    = (double)vraw;
        const double    av   = fabs(v);
        const long long bits = __double_as_longlong(v);
        const double    fl   = floor(av);

        // ---- text embedding ----
        const float* wrow = Ww + (size_t)NUM_TOKEN * HIDDEN;
        const float* prow = Wp + (size_t)s * HIDDEN;
        float x[4][4];
        #pragma unroll
        for (int j = 0; j < 4; ++j) {
            const int off = j * 256 + col0;
            const float4 aw = *(const float4*)(wrow + off);
            const float4 ap = *(const float4*)(prow + off);
            const float4 at = *(const float4*)(Wt   + off);
            x[j][0] = aw.x + ap.x + at.x;
            x[j][1] = aw.y + ap.y + at.y;
            x[j][2] = aw.z + ap.z + at.z;
            x[j][3] = aw.w + ap.w + at.w;
        }

        // ---- features: lane k owns feat[k] (f0) and feat[64+k] (f1) ----
        float f0 = (lane < 63 && ((bits >> lane) & 1LL)) ? 1.0f : 0.0f;
        float f1 = 0.0f;
        if (lane < 10) {
            const int units = (int)fmin(fmax(fmod(fl, 10.0), 0.0), 9.0);
            f1 = (lane == units) ? 1.0f : 0.0f;
        } else if (lane < 20) {
            const int tens = (int)fmin(fmax(fmod(floor(fl / 10.0), 10.0), 0.0), 9.0);
            f1 = (lane - 10 == tens) ? 1.0f : 0.0f;
        } else if (lane < 30) {
            switch (lane - 20) {
                case 0: f1 = (float)log(av + 1e-6); break;
                case 1: f1 = (v > 0.0) ? 1.0f : ((v < 0.0) ? -1.0f : 0.0f); break;
                case 2: f1 = (av > 1e-6) ? (float)floor(log10(fmax(av, 1e-300))) : 0.0f; break;
                case 3: f1 = (av == fl) ? 1.0f : 0.0f; break;
                case 4: f1 = (v > 0.0) ? 1.0f : 0.0f; break;
                case 5: f1 = (v == 0.0) ? 1.0f : 0.0f; break;
                case 6: f1 = (v < 0.0) ? 1.0f : 0.0f; break;
                case 7: {
                    const bool   pos_int = (v == floor(v)) && (v > 0.0);
                    const double l2      = log2(fmax(v, 1.0));
                    f1 = (pos_int && (l2 == floor(l2))) ? 1.0f : 0.0f;
                    break;
                }
                case 8: f1 = (fmt == 0) ? 1.0f : 0.0f; break;
                case 9: f1 = (fmt == 1) ? 1.0f : 0.0f; break;
            }
        }

        // ---- h = gelu(feats @ w1 + b1), lane owns o = lane + 64*i ----
        float acc[4] = { b1[lane], b1[lane + 64], b1[lane + 128], b1[lane + 192] };
        for (int k = 0; k < 64; ++k) {
            const float  fk  = __shfl(f0, k, 64);
            const float* col = w1 + k * PI;
            acc[0] = fmaf(fk, col[lane],       acc[0]);
            acc[1] = fmaf(fk, col[lane + 64],  acc[1]);
            acc[2] = fmaf(fk, col[lane + 128], acc[2]);
            acc[3] = fmaf(fk, col[lane + 192], acc[3]);
        }
        for (int k = 0; k < NF - 64; ++k) {
            const float  fk  = __shfl(f1, k, 64);
            const float* col = w1 + (64 + k) * PI;
            acc[0] = fmaf(fk, col[lane],       acc[0]);
            acc[1] = fmaf(fk, col[lane + 64],  acc[1]);
            acc[2] = fmaf(fk, col[lane + 128], acc[2]);
            acc[3] = fmaf(fk, col[lane + 192], acc[3]);
        }
        float h[4];
        #pragma unroll
        for (int i = 0; i < 4; ++i) h[i] = gelu_exact(acc[i]);

        // ---- n = h @ w2 + b2, lane owns d = j*256 + lane*4 + c ----
        float n[4][4];
        #pragma unroll
        for (int j = 0; j < 4; ++j) {
            const float4 bb = *(const float4*)(b2 + j * 256 + col0);
            n[j][0] = bb.x; n[j][1] = bb.y; n[j][2] = bb.z; n[j][3] = bb.w;
        }
        #pragma unroll
        for (int i = 0; i < 4; ++i) {
            for (int kk = 0; kk < 64; ++kk) {
                const float  hk  = __shfl(h[i], kk, 64);
                const float* row = w2 + (size_t)(i * 64 + kk) * HIDDEN;
                #pragma unroll
                for (int j = 0; j < 4; ++j) {
                    const float4 w = *(const float4*)(row + j * 256 + col0);
                    n[j][0] = fmaf(hk, w.x, n[j][0]);
                    n[j][1] = fmaf(hk, w.y, n[j][1]);
                    n[j][2] = fmaf(hk, w.z, n[j][2]);
                    n[j][3] = fmaf(hk, w.w, n[j][3]);
                }
            }
        }

        // ---- projection LayerNorm (wave butterfly) ----
        float sm = 0.0f, sq = 0.0f;
        #pragma unroll
        for (int j = 0; j < 4; ++j)
            #pragma unroll
            for (int c = 0; c < 4; ++c) { sm += n[j][c]; sq += n[j][c] * n[j][c]; }
        #pragma unroll
        for (int off = 32; off > 0; off >>= 1) {
            sm += __shfl_xor(sm, off, 64);
            sq += __shfl_xor(sq, off, 64);
        }
        {
            const float mu   = sm * (1.0f / HIDDEN);
            const float var  = sq * (1.0f / HIDDEN) - mu * mu;
            const float rstd = rsqrtf(var + 1e-12f);
            #pragma unroll
            for (int j = 0; j < 4; ++j) {
                const float4 g4 = *(const float4*)(plng + j * 256 + col0);
                const float4 b4 = *(const float4*)(plnb + j * 256 + col0);
                x[j][0] += (n[j][0] - mu) * rstd * g4.x + b4.x;
                x[j][1] += (n[j][1] - mu) * rstd * g4.y + b4.y;
                x[j][2] += (n[j][2] - mu) * rstd * g4.z + b4.z;
                x[j][3] += (n[j][3] - mu) * rstd * g4.w + b4.w;
            }
        }

        // ---- final LayerNorm + overwrite the output row ----
        sm = 0.0f; sq = 0.0f;
        #pragma unroll
        for (int j = 0; j < 4; ++j)
            #pragma unroll
            for (int c = 0; c < 4; ++c) { sm += x[j][c]; sq += x[j][c] * x[j][c]; }
        #pragma unroll
        for (int off = 32; off > 0; off >>= 1) {
            sm += __shfl_xor(sm, off, 64);
            sq += __shfl_xor(sq, off, 64);
        }
        const float mu   = sm * (1.0f / HIDDEN);
        const float var  = sq * (1.0f / HIDDEN) - mu * mu;
        const float rstd = rsqrtf(var + 1e-12f);

        float* orow = out + (size_t)token * HIDDEN;
        #pragma unroll
        for (int j = 0; j < 4; ++j) {
            const int off = j * 256 + col0;
            const float4 g4 = *(const float4*)(lng + off);
            const float4 b4 = *(const float4*)(lnb + off);
            float4 o;
            o.x = (x[j][0] - mu) * rstd * g4.x + b4.x;
            o.y = (x[j][1] - mu) * rstd * g4.y + b4.y;
            o.z = (x[j][2] - mu) * rstd * g4.z + b4.z;
            o.w = (x[j][3] - mu) * rstd * g4.w + b4.w;
            *(float4*)(orow + off) = o;
        }
    }
}

extern "C" void kernel_launch(void* const* d_in, const int* in_sizes, int n_in,
                              void* d_out, int out_size, void* d_ws, size_t ws_size,
                              hipStream_t stream) {
    const int*   ids  = (const int*)d_in[0];
    const float* vals = (const float*)d_in[1];
    const int*   fmts = (const int*)d_in[2];
    const float* Ww   = (const float*)d_in[3];
    const float* Wp   = (const float*)d_in[4];
    const float* Wt   = (const float*)d_in[5];
    const float* lng  = (const float*)d_in[6];
    const float* lnb  = (const float*)d_in[7];
    const float* w1   = (const float*)d_in[8];
    const float* b1   = (const float*)d_in[9];
    const float* w2   = (const float*)d_in[10];
    const float* b2   = (const float*)d_in[11];
    const float* plng = (const float*)d_in[12];
    const float* plnb = (const float*)d_in[13];
    float* out = (float*)d_out;

    const int tokens = in_sizes[0];                 // 8 * 2048 = 16384

    // A: streaming text+LN for every token (lean registers, max occupancy)
    text_ln_kernel<<<(tokens + 3) / 4, 256, 0, stream>>>(
        ids, Ww, Wp, Wt, lng, lnb, out, tokens);

    // B: ballot-and-exit fixup for the rare active numeric tokens
    const int blocksB = (tokens + 255) / 256;       // 4 waves/block, 64 tokens/wave
    numeric_fix_kernel<<<blocksB, 256, 0, stream>>>(
        ids, vals, fmts, Ww, Wp, Wt, lng, lnb, w1, b1, w2, b2, plng, plnb, out, tokens);
}